// Round 10
// baseline (397.122 us; speedup 1.0000x reference)
//
#include <hip/hip_runtime.h>
#include <math.h>

#define DD 1024
#define HH 2048
#define NCB 512           // compute blocks; block NCB is the checker
#define NBAR 16

typedef float f32x4 __attribute__((ext_vector_type(4)));
typedef short short8 __attribute__((ext_vector_type(8)));

__device__ __forceinline__ float b2f(unsigned short u) {
    return __uint_as_float(((unsigned int)u) << 16);
}
__device__ __forceinline__ unsigned short f2b(float f) {
    unsigned int x = __float_as_uint(f);
    unsigned int r = (x + 0x7FFFu + ((x >> 16) & 1u)) >> 16;
    return (unsigned short)r;
}

// ---------------- precompute: transposes only ----------------
// blocks: [0,512) W1->W1T | [512,1536) W2->W2T | [1536,2048) W3->W3T
__global__ __launch_bounds__(256) void k_pre(const float* __restrict__ W1,
                                             const float* __restrict__ W2,
                                             const float* __restrict__ W3,
                                             unsigned short* __restrict__ W1T,
                                             unsigned short* __restrict__ W2T,
                                             unsigned short* __restrict__ W3T) {
    __shared__ float tile[64][65];
    const int b = blockIdx.x, t = threadIdx.x;
    const float* in; unsigned short* out; int R, C, bx, by;
    if (b < 512)       { int bb = b;        in = W1; out = W1T; R = DD; C = HH; bx = bb & 31; by = bb >> 5; }
    else if (b < 1536) { int bb = b - 512;  in = W2; out = W2T; R = HH; C = HH; bx = bb & 31; by = bb >> 5; }
    else               { int bb = b - 1536; in = W3; out = W3T; R = HH; C = DD; bx = bb & 15; by = bb >> 4; }
    const int c0 = bx * 64, r0 = by * 64;
    const int cc = t & 63, rb = t >> 6;
    #pragma unroll
    for (int p = 0; p < 16; ++p) {
        int rr = p * 4 + rb;
        tile[rr][cc] = in[(size_t)(r0 + rr) * C + c0 + cc];
    }
    __syncthreads();
    #pragma unroll
    for (int p = 0; p < 16; ++p) {
        int rr = p * 4 + rb;
        out[(size_t)(c0 + rr) * R + r0 + cc] = f2b(tile[cc][rr]);
    }
}

// ---------------- M = W1^T W3^T, P = M .* W2, c1 = W1^T b3; + sync-state zero ----------------
__global__ __launch_bounds__(256) void k_gemmP(const unsigned short* __restrict__ W1T,
                                               const float* __restrict__ W3,
                                               const float* __restrict__ W2,
                                               const float* __restrict__ b3,
                                               unsigned short* __restrict__ Mb,
                                               unsigned short* __restrict__ Pb,
                                               float* __restrict__ c1,
                                               unsigned* __restrict__ flags) {
    const int t = threadIdx.x;
    if (blockIdx.x == 0 && blockIdx.y == 0) {
        #pragma unroll
        for (int q = 0; q < 17; ++q) {
            int i = t + q * 256;
            if (i < 4112) flags[i] = 0u;   // 512 flags*8 + gen + divacc + divcnt
        }
    }
    __shared__ unsigned short At[128][40];
    __shared__ unsigned short Bt[128][40];
    const int m0 = blockIdx.y * 128;
    const int k0 = blockIdx.x * 128;
    const int r = t & 127, half = t >> 7;
    const int wv = t >> 6, l = t & 63;
    const int wr = wv >> 1, wc = wv & 1;
    const int fr = l & 15, fg = l >> 4;
    const bool do_c1 = (blockIdx.x == 0) && (t < 128);
    float c1acc = 0.f;

    f32x4 acc[4][4] = {};
    for (int i0 = 0; i0 < DD; i0 += 32) {
        {
            const float4* sa = (const float4*)(W1T + (size_t)(m0 + r) * DD + i0 + half * 16);
            float4 a0 = sa[0], a1 = sa[1];
            const float4* sbf = (const float4*)(W3 + (size_t)(k0 + r) * DD + i0 + half * 16);
            float4 f0 = sbf[0], f1 = sbf[1], f2v = sbf[2], f3 = sbf[3];
            float4* da = (float4*)&At[r][half * 16];
            da[0] = a0; da[1] = a1;
            short8 o0, o1;
            o0[0] = (short)f2b(f0.x); o0[1] = (short)f2b(f0.y); o0[2] = (short)f2b(f0.z); o0[3] = (short)f2b(f0.w);
            o0[4] = (short)f2b(f1.x); o0[5] = (short)f2b(f1.y); o0[6] = (short)f2b(f1.z); o0[7] = (short)f2b(f1.w);
            o1[0] = (short)f2b(f2v.x); o1[1] = (short)f2b(f2v.y); o1[2] = (short)f2b(f2v.z); o1[3] = (short)f2b(f2v.w);
            o1[4] = (short)f2b(f3.x); o1[5] = (short)f2b(f3.y); o1[6] = (short)f2b(f3.z); o1[7] = (short)f2b(f3.w);
            *(short8*)&Bt[r][half * 16] = o0;
            *(short8*)&Bt[r][half * 16 + 8] = o1;
        }
        __syncthreads();
        if (do_c1) {
            #pragma unroll
            for (int i = 0; i < 32; ++i)
                c1acc += b2f(At[t][i]) * b3[i0 + i];
        }
        short8 af[4], bf[4];
        #pragma unroll
        for (int a = 0; a < 4; ++a)
            af[a] = *(const short8*)&At[wr * 64 + a * 16 + fr][fg * 8];
        #pragma unroll
        for (int b = 0; b < 4; ++b)
            bf[b] = *(const short8*)&Bt[wc * 64 + b * 16 + fr][fg * 8];
        #pragma unroll
        for (int a = 0; a < 4; ++a)
            #pragma unroll
            for (int b = 0; b < 4; ++b)
                acc[a][b] = __builtin_amdgcn_mfma_f32_16x16x32_bf16(af[a], bf[b], acc[a][b], 0, 0, 0);
        __syncthreads();
    }
    if (do_c1) c1[m0 + t] = c1acc;
    #pragma unroll
    for (int a = 0; a < 4; ++a) {
        #pragma unroll
        for (int b = 0; b < 4; ++b) {
            #pragma unroll
            for (int j = 0; j < 4; ++j) {
                int row = m0 + wr * 64 + a * 16 + fg * 4 + j;
                int col = k0 + wc * 64 + b * 16 + fr;
                size_t idx = (size_t)row * HH + col;
                float m = acc[a][b][j];
                Mb[idx] = f2b(m);
                Pb[idx] = f2b(m * W2[idx]);
            }
        }
    }
}

// ---------------- checker grid barrier (R8-proven) ----------------
__device__ __forceinline__ void gbar(unsigned* flags, unsigned* gen, int b, unsigned g) {
    __syncthreads();
    if (threadIdx.x == 0) {
        __threadfence();
        __hip_atomic_store(&flags[b << 3], g, __ATOMIC_RELAXED, __HIP_MEMORY_SCOPE_AGENT);
        while (__hip_atomic_load(gen, __ATOMIC_RELAXED, __HIP_MEMORY_SCOPE_AGENT) < g)
            __builtin_amdgcn_s_sleep(1);
        __threadfence();
    }
    __syncthreads();
}

// ---------------- persistent RK4 chain: 512 blocks x 4 waves, M/P in LDS ----------------
__global__ __launch_bounds__(256) void k_chain(
    const unsigned short* __restrict__ Mb,   // [2048][2048]
    const unsigned short* __restrict__ Pb,   // [2048][2048]
    const unsigned short* __restrict__ W1T,  // [2048][1024]
    const unsigned short* __restrict__ W2T,  // [2048][2048]
    const unsigned short* __restrict__ W3T,  // [1024][2048]
    const float* __restrict__ x0,
    const float* __restrict__ b1, const float* __restrict__ wt,
    const float* __restrict__ b2, const float* __restrict__ b3,
    const float* __restrict__ c1,
    float* __restrict__ h1_g, float* __restrict__ h2_g, float* __restrict__ hacc_g,
    float* __restrict__ out,
    unsigned* __restrict__ flags) {
    unsigned* gen    = flags + 4096;
    unsigned* divacc = flags + 4100;   // float bits
    unsigned* divcnt = flags + 4104;
    const int t = threadIdx.x, b = blockIdx.x;

    // ---- checker block ----
    if (b == NCB) {
        if (t < 64) {
            for (unsigned g = 1; g <= NBAR; ++g) {
                while (true) {
                    bool ok = true;
                    #pragma unroll
                    for (int k = 0; k < 8; ++k) {
                        unsigned f = __hip_atomic_load(&flags[(t + (k << 6)) << 3],
                                                       __ATOMIC_RELAXED, __HIP_MEMORY_SCOPE_AGENT);
                        ok &= (f >= g);
                    }
                    if (!__any((int)(!ok))) break;
                    __builtin_amdgcn_s_sleep(1);
                }
                __threadfence();
                if (t == 0)
                    __hip_atomic_store(gen, g, __ATOMIC_RELAXED, __HIP_MEMORY_SCOPE_AGENT);
            }
        }
        return;
    }

    __shared__ unsigned short Ms[4][2048];   // 16 KB
    __shared__ unsigned short Ps[4][2048];   // 16 KB
    __shared__ float vecH[2048];             // 8 KB
    __shared__ float vecW[2048];             // 8 KB
    __shared__ float wred[4];
    const int wib = t >> 6, lane = t & 63;
    const int gw = (b << 2) + wib;   // 0..2047 -> one h-row per wave
    unsigned g = 0;

    // ---- preload this block's M,P rows into LDS (wave-private rows, no sync needed) ----
    {
        const unsigned short* mp = Mb + (size_t)gw * HH;
        const unsigned short* pp = Pb + (size_t)gw * HH;
        #pragma unroll
        for (int rep = 0; rep < 4; ++rep) {
            const int idx = rep * 512 + lane * 8;
            *(short8*)&Ms[wib][idx] = *(const short8*)(mp + idx);
            *(short8*)&Ps[wib][idx] = *(const short8*)(pp + idx);
        }
    }

    const float bb1 = b1[gw], wtv = wt[gw], bb2 = b2[gw], c1v = c1[gw];
    float A1 = 0.f, u = 0.f, hc = 0.f, wdiv = 0.f;

    float logq_r = 0.f;
    if (b == 0 && wib == 0) {
        float ssum = 0.f;
        #pragma unroll
        for (int q = 0; q < 16; ++q) { float xv = x0[lane + (q << 6)]; ssum += xv * xv; }
        #pragma unroll
        for (int o = 1; o < 64; o <<= 1) ssum += __shfl_xor(ssum, o, 64);
        logq_r = -0.5f * ssum - 0.5f * 1024.0f * 1.8378770664093453f;
    }

    for (int s = 0; s < 8; ++s) {
        const int ss = s & 3;
        const float tcur = (s >> 2) * 0.5f + ((ss == 0) ? 0.f : (ss == 3) ? 0.5f : 0.25f);

        // ================= Phase A: h1 (+ div ride-along for stage s-1) =================
        if (s == 0) {
            if (t < 256) ((float4*)vecH)[t] = ((const float4*)x0)[t];
            __syncthreads();
            float a0 = 0.f;
            const unsigned short* Wr = W1T + (size_t)gw * DD;
            #pragma unroll
            for (int rep = 0; rep < 2; ++rep) {
                const int idx = rep * 512 + lane * 8;
                short8 r0 = *(const short8*)(Wr + idx);
                float4 hA = *(const float4*)(vecH + idx);
                float4 hB = *(const float4*)(vecH + idx + 4);
                float hv[8] = {hA.x, hA.y, hA.z, hA.w, hB.x, hB.y, hB.z, hB.w};
                #pragma unroll
                for (int e = 0; e < 8; ++e) a0 += b2f((unsigned short)r0[e]) * hv[e];
            }
            #pragma unroll
            for (int o = 1; o < 64; o <<= 1) a0 += __shfl_xor(a0, o, 64);
            A1 = a0;
            float h0 = tanhf(A1 + bb1 + tcur * wtv);
            u = 1.f - h0 * h0;
            if (lane == 0) h1_g[gw] = h0;
        } else {
            {
                float4 ha = ((const float4*)h2_g)[t];
                float4 hb = ((const float4*)h2_g)[t + 256];
                float4 sa, sb;
                if (ss == 0) { sa = ((const float4*)hacc_g)[t]; sb = ((const float4*)hacc_g)[t + 256]; }
                else         { sa = ha; sb = hb; }
                ((float4*)vecH)[t] = sa;
                ((float4*)vecH)[t + 256] = sb;
                ((float4*)vecW)[t] = make_float4(1.f - ha.x * ha.x, 1.f - ha.y * ha.y,
                                                 1.f - ha.z * ha.z, 1.f - ha.w * ha.w);
                ((float4*)vecW)[t + 256] = make_float4(1.f - hb.x * hb.x, 1.f - hb.y * hb.y,
                                                       1.f - hb.z * hb.z, 1.f - hb.w * hb.w);
            }
            __syncthreads();
            float md = 0.f, pd = 0.f;
            #pragma unroll
            for (int rep = 0; rep < 4; ++rep) {
                const int idx = rep * 512 + lane * 8;
                short8 mv = *(const short8*)&Ms[wib][idx];
                short8 pv = *(const short8*)&Ps[wib][idx];
                float4 hA = *(const float4*)(vecH + idx);
                float4 hB = *(const float4*)(vecH + idx + 4);
                float4 wA = *(const float4*)(vecW + idx);
                float4 wB = *(const float4*)(vecW + idx + 4);
                float hv[8] = {hA.x, hA.y, hA.z, hA.w, hB.x, hB.y, hB.z, hB.w};
                float wv[8] = {wA.x, wA.y, wA.z, wA.w, wB.x, wB.y, wB.z, wB.w};
                #pragma unroll
                for (int e = 0; e < 8; ++e) {
                    md += b2f((unsigned short)mv[e]) * hv[e];
                    pd += b2f((unsigned short)pv[e]) * wv[e];
                }
            }
            #pragma unroll
            for (int o = 1; o < 64; o <<= 1) {
                md += __shfl_xor(md, o, 64); pd += __shfl_xor(pd, o, 64);
            }
            const int sp = (s - 1) & 3;
            const float cprev = (sp == 1 || sp == 2) ? (1.f / 6.f) : (1.f / 12.f);
            wdiv += cprev * u * pd;
            float pre;
            if (ss == 0) {                      // step boundary: A1 += M*hacc + dt*c1
                A1 += md + 0.5f * c1v;
                pre = A1 + bb1 + tcur * wtv;
            } else {
                const float a = (ss == 3) ? 0.5f : 0.25f;
                pre = A1 + a * (md + c1v) + bb1 + tcur * wtv;
            }
            float h0 = tanhf(pre);
            u = 1.f - h0 * h0;
            if (lane == 0) h1_g[gw] = h0;
        }
        gbar(flags, gen, b, ++g);

        // ================= Phase B: h2 = tanh(W2^T h1 + b2) =================
        ((float4*)vecH)[t] = ((const float4*)h1_g)[t];
        ((float4*)vecH)[t + 256] = ((const float4*)h1_g)[t + 256];
        __syncthreads();
        {
            float a0 = 0.f;
            const unsigned short* Wr = W2T + (size_t)gw * HH;
            #pragma unroll
            for (int rep = 0; rep < 4; ++rep) {
                const int idx = rep * 512 + lane * 8;
                short8 r0 = *(const short8*)(Wr + idx);
                float4 hA = *(const float4*)(vecH + idx);
                float4 hB = *(const float4*)(vecH + idx + 4);
                float hv[8] = {hA.x, hA.y, hA.z, hA.w, hB.x, hB.y, hB.z, hB.w};
                #pragma unroll
                for (int e = 0; e < 8; ++e) a0 += b2f((unsigned short)r0[e]) * hv[e];
            }
            #pragma unroll
            for (int o = 1; o < 64; o <<= 1) a0 += __shfl_xor(a0, o, 64);
            float q0 = tanhf(a0 + bb2);
            const float cs = (ss == 1 || ss == 2) ? (1.f / 6.f) : (1.f / 12.f);
            hc += cs * q0;
            if (lane == 0) {
                h2_g[gw] = q0;
                if (ss == 3) hacc_g[gw] = hc;
            }
        }
        gbar(flags, gen, b, ++g);
    }

    // ================= Epilogue: last div + x_out; logq via atomics =================
    {
        {
            float4 ha = ((const float4*)h2_g)[t];
            float4 hb = ((const float4*)h2_g)[t + 256];
            ((float4*)vecH)[t] = ((const float4*)hacc_g)[t];
            ((float4*)vecH)[t + 256] = ((const float4*)hacc_g)[t + 256];
            ((float4*)vecW)[t] = make_float4(1.f - ha.x * ha.x, 1.f - ha.y * ha.y,
                                             1.f - ha.z * ha.z, 1.f - ha.w * ha.w);
            ((float4*)vecW)[t + 256] = make_float4(1.f - hb.x * hb.x, 1.f - hb.y * hb.y,
                                                   1.f - hb.z * hb.z, 1.f - hb.w * hb.w);
        }
        __syncthreads();
        float pd = 0.f, xo = 0.f;
        const unsigned short* Vr = (gw < DD) ? (W3T + (size_t)gw * HH) : W3T;
        #pragma unroll
        for (int rep = 0; rep < 4; ++rep) {
            const int idx = rep * 512 + lane * 8;
            short8 pv = *(const short8*)&Ps[wib][idx];
            short8 vv = *(const short8*)(Vr + idx);
            float4 hA = *(const float4*)(vecH + idx);
            float4 hB = *(const float4*)(vecH + idx + 4);
            float4 wA = *(const float4*)(vecW + idx);
            float4 wB = *(const float4*)(vecW + idx + 4);
            float hv[8] = {hA.x, hA.y, hA.z, hA.w, hB.x, hB.y, hB.z, hB.w};
            float wv[8] = {wA.x, wA.y, wA.z, wA.w, wB.x, wB.y, wB.z, wB.w};
            #pragma unroll
            for (int e = 0; e < 8; ++e) {
                pd += b2f((unsigned short)pv[e]) * wv[e];
                xo += b2f((unsigned short)vv[e]) * hv[e];
            }
        }
        #pragma unroll
        for (int o = 1; o < 64; o <<= 1) {
            pd += __shfl_xor(pd, o, 64); xo += __shfl_xor(xo, o, 64);
        }
        wdiv += (1.f / 12.f) * u * pd;
        if (lane == 0) {
            if (gw < DD) out[gw] = x0[gw] + xo + b3[gw];
            wred[wib] = wdiv;
        }
    }
    __syncthreads();
    if (t == 0) {
        float dsum = wred[0] + wred[1] + wred[2] + wred[3];
        atomicAdd((float*)divacc, dsum);
        __threadfence();
        atomicAdd(divcnt, 1u);
    }
    if (b == 0 && t == 0) {
        while (__hip_atomic_load(divcnt, __ATOMIC_RELAXED, __HIP_MEMORY_SCOPE_AGENT) < NCB)
            __builtin_amdgcn_s_sleep(1);
        __threadfence();
        unsigned du = __hip_atomic_load(divacc, __ATOMIC_RELAXED, __HIP_MEMORY_SCOPE_AGENT);
        out[DD] = logq_r - __uint_as_float(du);
    }
}

extern "C" void kernel_launch(void* const* d_in, const int* in_sizes, int n_in,
                              void* d_out, int out_size, void* d_ws, size_t ws_size,
                              hipStream_t stream) {
    const float* x0 = (const float*)d_in[0];
    const float* W1 = (const float*)d_in[1];
    const float* b1 = (const float*)d_in[2];
    const float* wt = (const float*)d_in[3];
    const float* W2 = (const float*)d_in[4];
    const float* b2 = (const float*)d_in[5];
    const float* W3 = (const float*)d_in[6];
    const float* b3 = (const float*)d_in[7];
    float* out = (float*)d_out;

    char* ws = (char*)d_ws;
    const size_t MB = 1024 * 1024;
    unsigned short* Pb  = (unsigned short*)(ws);            // 8 MB
    unsigned short* W1T = (unsigned short*)(ws + 8 * MB);   // 4 MB
    unsigned short* W2T = (unsigned short*)(ws + 12 * MB);  // 8 MB
    unsigned short* W3T = (unsigned short*)(ws + 20 * MB);  // 4 MB
    unsigned short* Mb  = (unsigned short*)(ws + 24 * MB);  // 8 MB
    float* fb = (float*)(ws + 32 * MB);
    float* h1_g    = fb;                       // 2048
    float* h2_g    = fb + 2048;                // 2048
    float* hacc_g  = fb + 4096;                // 2048
    float* c1      = fb + 6144;                // 2048
    unsigned* flags = (unsigned*)(fb + 8192);  // 4112 uints: flags+gen+divacc+divcnt

    k_pre<<<2048, 256, 0, stream>>>(W1, W2, W3, W1T, W2T, W3T);
    k_gemmP<<<dim3(16, 16), 256, 0, stream>>>(W1T, W3, W2, b3, Mb, Pb, c1, flags);
    k_chain<<<NCB + 1, 256, 0, stream>>>(Mb, Pb, W1T, W2T, W3T, x0, b1, wt, b2, b3, c1,
                                         h1_g, h2_g, hacc_g, out, flags);
}

// Round 11
// 253.654 us; speedup vs baseline: 1.5656x; 1.5656x over previous
//
#include <hip/hip_runtime.h>
#include <math.h>

#define DD 1024
#define HH 2048
#define NCB 256           // compute blocks, 16 sectors x 16

typedef float f32x4 __attribute__((ext_vector_type(4)));
typedef short short8 __attribute__((ext_vector_type(8)));

__device__ __forceinline__ float b2f(unsigned short u) {
    return __uint_as_float(((unsigned int)u) << 16);
}
__device__ __forceinline__ unsigned short f2b(float f) {
    unsigned int x = __float_as_uint(f);
    unsigned int r = (x + 0x7FFFu + ((x >> 16) & 1u)) >> 16;
    return (unsigned short)r;
}

// ---------------- W1 -> W1T (bf16) + zero sync state ----------------
__global__ __launch_bounds__(256) void k_preW1(const float* __restrict__ W1,
                                               unsigned short* __restrict__ W1T,
                                               unsigned* __restrict__ sync) {
    __shared__ float tile[64][65];
    const int b = blockIdx.x, t = threadIdx.x;
    if (b == 0) {
        #pragma unroll
        for (int q = 0; q < 4; ++q) sync[t + q * 256] = 0u;
    }
    const int bx = b & 31, by = b >> 5;          // 32 col-blocks x 16 row-blocks
    const int c0 = bx * 64, r0 = by * 64;
    const int cc = t & 63, rb = t >> 6;
    #pragma unroll
    for (int p = 0; p < 16; ++p) {
        int rr = p * 4 + rb;
        tile[rr][cc] = W1[(size_t)(r0 + rr) * HH + c0 + cc];
    }
    __syncthreads();
    #pragma unroll
    for (int p = 0; p < 16; ++p) {
        int rr = p * 4 + rb;
        W1T[(size_t)(c0 + rr) * DD + r0 + cc] = f2b(tile[cc][rr]);
    }
}

// ---------------- merged: [0,256) gemm M,P,c1,A1 | [256,1792) W2T/W3T transposes ----------------
__global__ __launch_bounds__(256) void k_gemmPT(const unsigned short* __restrict__ W1T,
                                                const float* __restrict__ W2,
                                                const float* __restrict__ W3,
                                                const float* __restrict__ b3,
                                                const float* __restrict__ x0,
                                                unsigned short* __restrict__ Mb,
                                                unsigned short* __restrict__ Pb,
                                                unsigned short* __restrict__ W2T,
                                                unsigned short* __restrict__ W3T,
                                                float* __restrict__ c1,
                                                float* __restrict__ A1g) {
    const int b = blockIdx.x, t = threadIdx.x;
    if (b >= 256) {
        // ---- transpose part ----
        __shared__ float tile[64][65];
        int bb = b - 256;
        const float* in; unsigned short* out; int R, C, bx, by;
        if (bb < 1024) { in = W2; out = W2T; R = HH; C = HH; bx = bb & 31; by = bb >> 5; }
        else           { bb -= 1024; in = W3; out = W3T; R = HH; C = DD; bx = bb & 15; by = bb >> 4; }
        const int c0 = bx * 64, r0 = by * 64;
        const int cc = t & 63, rb = t >> 6;
        #pragma unroll
        for (int p = 0; p < 16; ++p) {
            int rr = p * 4 + rb;
            tile[rr][cc] = in[(size_t)(r0 + rr) * C + c0 + cc];
        }
        __syncthreads();
        #pragma unroll
        for (int p = 0; p < 16; ++p) {
            int rr = p * 4 + rb;
            out[(size_t)(c0 + rr) * R + r0 + cc] = f2b(tile[cc][rr]);
        }
        return;
    }
    // ---- gemm part: M = W1^T W3^T, P = M .* W2, c1 = W1^T b3, A1 = W1^T x0 ----
    __shared__ unsigned short At[128][40];
    __shared__ unsigned short Bt[128][40];
    const int m0 = (b >> 4) * 128;
    const int k0 = (b & 15) * 128;
    const int r = t & 127, half = t >> 7;
    const int wv = t >> 6, l = t & 63;
    const int wr = wv >> 1, wc = wv & 1;
    const int fr = l & 15, fg = l >> 4;
    const bool do_c1 = ((b & 15) == 0) && (t < 128);
    float c1acc = 0.f, a1acc = 0.f;

    f32x4 acc[4][4] = {};
    for (int i0 = 0; i0 < DD; i0 += 32) {
        {
            const float4* sa = (const float4*)(W1T + (size_t)(m0 + r) * DD + i0 + half * 16);
            float4 a0 = sa[0], a1 = sa[1];
            const float4* sbf = (const float4*)(W3 + (size_t)(k0 + r) * DD + i0 + half * 16);
            float4 f0 = sbf[0], f1 = sbf[1], f2v = sbf[2], f3 = sbf[3];
            float4* da = (float4*)&At[r][half * 16];
            da[0] = a0; da[1] = a1;
            short8 o0, o1;
            o0[0] = (short)f2b(f0.x); o0[1] = (short)f2b(f0.y); o0[2] = (short)f2b(f0.z); o0[3] = (short)f2b(f0.w);
            o0[4] = (short)f2b(f1.x); o0[5] = (short)f2b(f1.y); o0[6] = (short)f2b(f1.z); o0[7] = (short)f2b(f1.w);
            o1[0] = (short)f2b(f2v.x); o1[1] = (short)f2b(f2v.y); o1[2] = (short)f2b(f2v.z); o1[3] = (short)f2b(f2v.w);
            o1[4] = (short)f2b(f3.x); o1[5] = (short)f2b(f3.y); o1[6] = (short)f2b(f3.z); o1[7] = (short)f2b(f3.w);
            *(short8*)&Bt[r][half * 16] = o0;
            *(short8*)&Bt[r][half * 16 + 8] = o1;
        }
        __syncthreads();
        if (do_c1) {
            #pragma unroll
            for (int i = 0; i < 32; ++i) {
                float w1v = b2f(At[t][i]);
                c1acc += w1v * b3[i0 + i];
                a1acc += w1v * x0[i0 + i];
            }
        }
        short8 af[4], bf[4];
        #pragma unroll
        for (int a = 0; a < 4; ++a)
            af[a] = *(const short8*)&At[wr * 64 + a * 16 + fr][fg * 8];
        #pragma unroll
        for (int bq = 0; bq < 4; ++bq)
            bf[bq] = *(const short8*)&Bt[wc * 64 + bq * 16 + fr][fg * 8];
        #pragma unroll
        for (int a = 0; a < 4; ++a)
            #pragma unroll
            for (int bq = 0; bq < 4; ++bq)
                acc[a][bq] = __builtin_amdgcn_mfma_f32_16x16x32_bf16(af[a], bf[bq], acc[a][bq], 0, 0, 0);
        __syncthreads();
    }
    if (do_c1) { c1[m0 + t] = c1acc; A1g[m0 + t] = a1acc; }
    #pragma unroll
    for (int a = 0; a < 4; ++a) {
        #pragma unroll
        for (int bq = 0; bq < 4; ++bq) {
            #pragma unroll
            for (int j = 0; j < 4; ++j) {
                int row = m0 + wr * 64 + a * 16 + fg * 4 + j;
                int col = k0 + wc * 64 + bq * 16 + fr;
                size_t idx = (size_t)row * HH + col;
                float m = acc[a][bq][j];
                Mb[idx] = f2b(m);
                Pb[idx] = f2b(m * W2[idx]);
            }
        }
    }
}

// ---------------- sector-tree grid barrier: 16x16, RMW arrival, load-poll release ----------------
// sync layout (uints, 64B lines): scnt[sec]=sync+sec*16 (lines 0..15), rcnt=sync+256,
// sgen[sec]=sync+272+sec*16 (lines 17..32), divacc[sec]=sync+528+sec*16 (lines 33..48)
__device__ __forceinline__ void gbar(unsigned* sync, int b, unsigned g) {
    __syncthreads();
    if (threadIdx.x == 0) {
        const int sec = b & 15;
        unsigned* scnt = sync + sec * 16;
        unsigned* rcnt = sync + 256;
        unsigned* sgen = sync + 272 + sec * 16;
        __threadfence();
        unsigned a = __hip_atomic_fetch_add(scnt, 1u, __ATOMIC_RELAXED, __HIP_MEMORY_SCOPE_AGENT);
        if (a == 16u * g - 1u) {
            unsigned rr = __hip_atomic_fetch_add(rcnt, 1u, __ATOMIC_RELAXED, __HIP_MEMORY_SCOPE_AGENT);
            if (rr == 16u * g - 1u) {
                #pragma unroll
                for (int q = 0; q < 16; ++q)
                    __hip_atomic_store(sync + 272 + q * 16, g, __ATOMIC_RELAXED, __HIP_MEMORY_SCOPE_AGENT);
            } else {
                while (__hip_atomic_load(sgen, __ATOMIC_RELAXED, __HIP_MEMORY_SCOPE_AGENT) < g)
                    __builtin_amdgcn_s_sleep(2);
            }
        } else {
            while (__hip_atomic_load(sgen, __ATOMIC_RELAXED, __HIP_MEMORY_SCOPE_AGENT) < g)
                __builtin_amdgcn_s_sleep(2);
        }
        __threadfence();
    }
    __syncthreads();
}

// ---------------- persistent RK4 chain: 256 blocks x 4 waves, M/P rows in LDS ----------------
__global__ __launch_bounds__(256, 1) void k_chain(
    const unsigned short* __restrict__ Mb,   // [2048][2048]
    const unsigned short* __restrict__ Pb,   // [2048][2048]
    const unsigned short* __restrict__ W2T,  // [2048][2048]
    const unsigned short* __restrict__ W3T,  // [1024][2048]
    const float* __restrict__ x0,
    const float* __restrict__ b1, const float* __restrict__ wt,
    const float* __restrict__ b2, const float* __restrict__ b3,
    const float* __restrict__ c1, const float* __restrict__ A1g,
    float* __restrict__ h1_g, float* __restrict__ h2_g, float* __restrict__ hacc_g,
    float* __restrict__ out,
    unsigned* __restrict__ sync) {
    __shared__ unsigned short MsL[8][2048];   // 32 KB: this block's 8 M-rows
    __shared__ unsigned short PsL[8][2048];   // 32 KB: this block's 8 P-rows
    const int t = threadIdx.x, b = blockIdx.x;
    const int wib = t >> 6, lane = t & 63;
    const int gw2 = (b << 3) + (wib << 1);    // h-row pair base (2 rows/wave)
    const int jx = (b << 2) + wib;            // x-row (1/wave, 0..1023)
    unsigned g = 0;

    // ---- preload this block's M,P rows into LDS (wave-private rows) ----
    {
        const unsigned short* mp = Mb + (size_t)gw2 * HH;
        const unsigned short* pp = Pb + (size_t)gw2 * HH;
        #pragma unroll
        for (int rep = 0; rep < 4; ++rep) {
            const int idx = rep * 512 + lane * 8;
            *(short8*)&MsL[wib * 2][idx]     = *(const short8*)(mp + idx);
            *(short8*)&MsL[wib * 2 + 1][idx] = *(const short8*)(mp + HH + idx);
            *(short8*)&PsL[wib * 2][idx]     = *(const short8*)(pp + idx);
            *(short8*)&PsL[wib * 2 + 1][idx] = *(const short8*)(pp + HH + idx);
        }
    }

    const float bb1_0 = b1[gw2], bb1_1 = b1[gw2 + 1];
    const float wt_0 = wt[gw2], wt_1 = wt[gw2 + 1];
    const float bb2_0 = b2[gw2], bb2_1 = b2[gw2 + 1];
    const float c1_0 = c1[gw2], c1_1 = c1[gw2 + 1];

    float A1_0 = 0.f, A1_1 = 0.f;
    float u0 = 0.f, u1 = 0.f;
    float hc0 = 0.f, hc1 = 0.f;
    float wdiv = 0.f;

    float logq_r = 0.f;
    if (b == 0 && wib == 0) {
        float ssum = 0.f;
        #pragma unroll
        for (int q = 0; q < 16; ++q) { float xv = x0[lane + (q << 6)]; ssum += xv * xv; }
        #pragma unroll
        for (int o = 1; o < 64; o <<= 1) ssum += __shfl_xor(ssum, o, 64);
        logq_r = -0.5f * ssum - 0.5f * 1024.0f * 1.8378770664093453f;
    }

    for (int s = 0; s < 8; ++s) {
        const int ss = s & 3;
        const float tcur = (s >> 2) * 0.5f + ((ss == 0) ? 0.f : (ss == 3) ? 0.5f : 0.25f);

        // ================= Phase A: h1 (+ div ride-along for stage s-1) =================
        if (s == 0) {
            A1_0 = A1g[gw2]; A1_1 = A1g[gw2 + 1];
            float h0 = tanhf(A1_0 + bb1_0 + tcur * wt_0);
            float h1v = tanhf(A1_1 + bb1_1 + tcur * wt_1);
            u0 = 1.f - h0 * h0; u1 = 1.f - h1v * h1v;
            if (lane == 0) *(float2*)(h1_g + gw2) = make_float2(h0, h1v);
        } else {
            float md0 = 0.f, md1 = 0.f, pd0 = 0.f, pd1 = 0.f;
            #pragma unroll
            for (int rep = 0; rep < 4; ++rep) {
                const int idx = rep * 512 + lane * 8;
                float4 hA = *(const float4*)(h2_g + idx);
                float4 hB = *(const float4*)(h2_g + idx + 4);
                float hv[8] = {hA.x, hA.y, hA.z, hA.w, hB.x, hB.y, hB.z, hB.w};
                float sv[8];
                if (ss == 0) {
                    float4 cA = *(const float4*)(hacc_g + idx);
                    float4 cB = *(const float4*)(hacc_g + idx + 4);
                    sv[0] = cA.x; sv[1] = cA.y; sv[2] = cA.z; sv[3] = cA.w;
                    sv[4] = cB.x; sv[5] = cB.y; sv[6] = cB.z; sv[7] = cB.w;
                } else {
                    #pragma unroll
                    for (int e = 0; e < 8; ++e) sv[e] = hv[e];
                }
                short8 m0v = *(const short8*)&MsL[wib * 2][idx];
                short8 m1v = *(const short8*)&MsL[wib * 2 + 1][idx];
                short8 p0v = *(const short8*)&PsL[wib * 2][idx];
                short8 p1v = *(const short8*)&PsL[wib * 2 + 1][idx];
                #pragma unroll
                for (int e = 0; e < 8; ++e) {
                    float wk = 1.f - hv[e] * hv[e];
                    md0 += b2f((unsigned short)m0v[e]) * sv[e];
                    md1 += b2f((unsigned short)m1v[e]) * sv[e];
                    pd0 += b2f((unsigned short)p0v[e]) * wk;
                    pd1 += b2f((unsigned short)p1v[e]) * wk;
                }
            }
            #pragma unroll
            for (int o = 1; o < 64; o <<= 1) {
                md0 += __shfl_xor(md0, o, 64); md1 += __shfl_xor(md1, o, 64);
                pd0 += __shfl_xor(pd0, o, 64); pd1 += __shfl_xor(pd1, o, 64);
            }
            const int sp = (s - 1) & 3;
            const float cprev = (sp == 1 || sp == 2) ? (1.f / 6.f) : (1.f / 12.f);
            wdiv += cprev * (u0 * pd0 + u1 * pd1);
            float pre0, pre1;
            if (ss == 0) {                      // step boundary: A1 += M*hacc + dt*c1
                A1_0 += md0 + 0.5f * c1_0; A1_1 += md1 + 0.5f * c1_1;
                pre0 = A1_0 + bb1_0 + tcur * wt_0; pre1 = A1_1 + bb1_1 + tcur * wt_1;
            } else {
                const float a = (ss == 3) ? 0.5f : 0.25f;
                pre0 = A1_0 + a * (md0 + c1_0) + bb1_0 + tcur * wt_0;
                pre1 = A1_1 + a * (md1 + c1_1) + bb1_1 + tcur * wt_1;
            }
            float h0 = tanhf(pre0), h1v = tanhf(pre1);
            u0 = 1.f - h0 * h0; u1 = 1.f - h1v * h1v;
            if (lane == 0) *(float2*)(h1_g + gw2) = make_float2(h0, h1v);
        }
        gbar(sync, b, ++g);

        // ================= Phase B: h2 = tanh(W2^T h1 + b2) =================
        {
            float a0 = 0.f, a1 = 0.f;
            const unsigned short* Wr = W2T + (size_t)gw2 * HH;
            #pragma unroll
            for (int rep = 0; rep < 4; ++rep) {
                const int idx = rep * 512 + lane * 8;
                short8 r0 = *(const short8*)(Wr + idx);
                short8 r1 = *(const short8*)(Wr + HH + idx);
                float4 hA = *(const float4*)(h1_g + idx);
                float4 hB = *(const float4*)(h1_g + idx + 4);
                float hv[8] = {hA.x, hA.y, hA.z, hA.w, hB.x, hB.y, hB.z, hB.w};
                #pragma unroll
                for (int e = 0; e < 8; ++e) {
                    a0 += b2f((unsigned short)r0[e]) * hv[e];
                    a1 += b2f((unsigned short)r1[e]) * hv[e];
                }
            }
            #pragma unroll
            for (int o = 1; o < 64; o <<= 1) {
                a0 += __shfl_xor(a0, o, 64); a1 += __shfl_xor(a1, o, 64);
            }
            float q0 = tanhf(a0 + bb2_0), q1 = tanhf(a1 + bb2_1);
            const float cs = (ss == 1 || ss == 2) ? (1.f / 6.f) : (1.f / 12.f);
            hc0 += cs * q0; hc1 += cs * q1;
            if (lane == 0) {
                *(float2*)(h2_g + gw2) = make_float2(q0, q1);
                if (ss == 3) *(float2*)(hacc_g + gw2) = make_float2(hc0, hc1);
            }
        }
        gbar(sync, b, ++g);
    }

    // ================= Epilogue: last div + x_out; logq via sector atomics =================
    {
        float pd0 = 0.f, pd1 = 0.f, xo = 0.f;
        const unsigned short* Vr = W3T + (size_t)jx * HH;
        #pragma unroll
        for (int rep = 0; rep < 4; ++rep) {
            const int idx = rep * 512 + lane * 8;
            float4 hA = *(const float4*)(h2_g + idx);
            float4 hB = *(const float4*)(h2_g + idx + 4);
            float4 cA = *(const float4*)(hacc_g + idx);
            float4 cB = *(const float4*)(hacc_g + idx + 4);
            float hv[8] = {hA.x, hA.y, hA.z, hA.w, hB.x, hB.y, hB.z, hB.w};
            float cv[8] = {cA.x, cA.y, cA.z, cA.w, cB.x, cB.y, cB.z, cB.w};
            short8 p0v = *(const short8*)&PsL[wib * 2][idx];
            short8 p1v = *(const short8*)&PsL[wib * 2 + 1][idx];
            short8 vv = *(const short8*)(Vr + idx);
            #pragma unroll
            for (int e = 0; e < 8; ++e) {
                float wk = 1.f - hv[e] * hv[e];
                pd0 += b2f((unsigned short)p0v[e]) * wk;
                pd1 += b2f((unsigned short)p1v[e]) * wk;
                xo  += b2f((unsigned short)vv[e]) * cv[e];
            }
        }
        #pragma unroll
        for (int o = 1; o < 64; o <<= 1) {
            pd0 += __shfl_xor(pd0, o, 64); pd1 += __shfl_xor(pd1, o, 64);
            xo += __shfl_xor(xo, o, 64);
        }
        wdiv += (1.f / 12.f) * (u0 * pd0 + u1 * pd1);
        if (lane == 0) {
            out[jx] = x0[jx] + xo + b3[jx];
            ((float*)MsL)[wib] = wdiv;   // MsL dead after s=7 phase A
        }
    }
    __syncthreads();
    if (t == 0) {
        float dsum = ((float*)MsL)[0] + ((float*)MsL)[1] + ((float*)MsL)[2] + ((float*)MsL)[3];
        atomicAdd((float*)(sync + 528 + (b & 15) * 16), dsum);
    }
    gbar(sync, b, ++g);
    if (b == 0 && wib == 0) {
        float v = 0.f;
        if (lane < 16) {
            unsigned du = __hip_atomic_load(sync + 528 + lane * 16, __ATOMIC_RELAXED, __HIP_MEMORY_SCOPE_AGENT);
            v = __uint_as_float(du);
        }
        #pragma unroll
        for (int o = 1; o < 64; o <<= 1) v += __shfl_xor(v, o, 64);
        if (lane == 0) out[DD] = logq_r - v;
    }
}

extern "C" void kernel_launch(void* const* d_in, const int* in_sizes, int n_in,
                              void* d_out, int out_size, void* d_ws, size_t ws_size,
                              hipStream_t stream) {
    const float* x0 = (const float*)d_in[0];
    const float* W1 = (const float*)d_in[1];
    const float* b1 = (const float*)d_in[2];
    const float* wt = (const float*)d_in[3];
    const float* W2 = (const float*)d_in[4];
    const float* b2 = (const float*)d_in[5];
    const float* W3 = (const float*)d_in[6];
    const float* b3 = (const float*)d_in[7];
    float* out = (float*)d_out;

    char* ws = (char*)d_ws;
    const size_t MB = 1024 * 1024;
    unsigned short* Pb  = (unsigned short*)(ws);            // 8 MB
    unsigned short* W1T = (unsigned short*)(ws + 8 * MB);   // 4 MB
    unsigned short* W2T = (unsigned short*)(ws + 12 * MB);  // 8 MB
    unsigned short* W3T = (unsigned short*)(ws + 20 * MB);  // 4 MB
    unsigned short* Mb  = (unsigned short*)(ws + 24 * MB);  // 8 MB
    float* fb = (float*)(ws + 32 * MB);
    float* h1_g    = fb;                       // 2048
    float* h2_g    = fb + 2048;                // 2048
    float* hacc_g  = fb + 4096;                // 2048
    float* c1      = fb + 6144;                // 2048
    float* A1g     = fb + 8192;                // 2048
    unsigned* sync = (unsigned*)(fb + 10240);  // 1024 uints (64B-aligned)

    k_preW1<<<512, 256, 0, stream>>>(W1, W1T, sync);
    k_gemmPT<<<1792, 256, 0, stream>>>(W1T, W2, W3, b3, x0, Mb, Pb, W2T, W3T, c1, A1g);
    k_chain<<<NCB, 256, 0, stream>>>(Mb, Pb, W2T, W3T, x0, b1, wt, b2, b3, c1, A1g,
                                     h1_g, h2_g, hacc_g, out, sync);
}

// Round 12
// 167.945 us; speedup vs baseline: 2.3646x; 1.5103x over previous
//
#include <hip/hip_runtime.h>
#include <math.h>

#define DD 1024
#define HH 2048
#define NCB 256

typedef float f32x4 __attribute__((ext_vector_type(4)));
typedef short short8 __attribute__((ext_vector_type(8)));

__device__ __forceinline__ float b2f(unsigned short u) {
    return __uint_as_float(((unsigned int)u) << 16);
}
__device__ __forceinline__ unsigned short f2b(float f) {
    unsigned int x = __float_as_uint(f);
    unsigned int r = (x + 0x7FFFu + ((x >> 16) & 1u)) >> 16;
    return (unsigned short)r;
}
__device__ __forceinline__ float ald(const float* p) {
    return __hip_atomic_load(p, __ATOMIC_RELAXED, __HIP_MEMORY_SCOPE_AGENT);
}
__device__ __forceinline__ void ast(float* p, float v) {
    __hip_atomic_store(p, v, __ATOMIC_RELAXED, __HIP_MEMORY_SCOPE_AGENT);
}

// ---------------- W1 -> W1T (bf16) + zero sync state ----------------
__global__ __launch_bounds__(256) void k_preW1(const float* __restrict__ W1,
                                               unsigned short* __restrict__ W1T,
                                               unsigned* __restrict__ sync) {
    __shared__ float tile[64][65];
    const int b = blockIdx.x, t = threadIdx.x;
    if (b == 0) {
        #pragma unroll
        for (int q = 0; q < 19; ++q) {
            int i = t + q * 256;
            if (i < 4624) sync[i] = 0u;
        }
    }
    const int bx = b & 31, by = b >> 5;
    const int c0 = bx * 64, r0 = by * 64;
    const int cc = t & 63, rb = t >> 6;
    #pragma unroll
    for (int p = 0; p < 16; ++p) {
        int rr = p * 4 + rb;
        tile[rr][cc] = W1[(size_t)(r0 + rr) * HH + c0 + cc];
    }
    __syncthreads();
    #pragma unroll
    for (int p = 0; p < 16; ++p) {
        int rr = p * 4 + rb;
        W1T[(size_t)(c0 + rr) * DD + r0 + cc] = f2b(tile[cc][rr]);
    }
}

// ---------------- merged: [0,256) gemm M,P,c1,A1 | [256,1792) W2T/W3T transposes ----------------
__global__ __launch_bounds__(256) void k_gemmPT(const unsigned short* __restrict__ W1T,
                                                const float* __restrict__ W2,
                                                const float* __restrict__ W3,
                                                const float* __restrict__ b3,
                                                const float* __restrict__ x0,
                                                unsigned short* __restrict__ Mb,
                                                unsigned short* __restrict__ Pb,
                                                unsigned short* __restrict__ W2T,
                                                unsigned short* __restrict__ W3T,
                                                float* __restrict__ c1,
                                                float* __restrict__ A1g) {
    const int b = blockIdx.x, t = threadIdx.x;
    if (b >= 256) {
        __shared__ float tile[64][65];
        int bb = b - 256;
        const float* in; unsigned short* out; int R, C, bx, by;
        if (bb < 1024) { in = W2; out = W2T; R = HH; C = HH; bx = bb & 31; by = bb >> 5; }
        else           { bb -= 1024; in = W3; out = W3T; R = HH; C = DD; bx = bb & 15; by = bb >> 4; }
        const int c0 = bx * 64, r0 = by * 64;
        const int cc = t & 63, rb = t >> 6;
        #pragma unroll
        for (int p = 0; p < 16; ++p) {
            int rr = p * 4 + rb;
            tile[rr][cc] = in[(size_t)(r0 + rr) * C + c0 + cc];
        }
        __syncthreads();
        #pragma unroll
        for (int p = 0; p < 16; ++p) {
            int rr = p * 4 + rb;
            out[(size_t)(c0 + rr) * R + r0 + cc] = f2b(tile[cc][rr]);
        }
        return;
    }
    __shared__ unsigned short At[128][40];
    __shared__ unsigned short Bt[128][40];
    const int m0 = (b >> 4) * 128;
    const int k0 = (b & 15) * 128;
    const int r = t & 127, half = t >> 7;
    const int wv = t >> 6, l = t & 63;
    const int wr = wv >> 1, wc = wv & 1;
    const int fr = l & 15, fg = l >> 4;
    const bool do_c1 = ((b & 15) == 0) && (t < 128);
    float c1acc = 0.f, a1acc = 0.f;

    f32x4 acc[4][4] = {};
    for (int i0 = 0; i0 < DD; i0 += 32) {
        {
            const float4* sa = (const float4*)(W1T + (size_t)(m0 + r) * DD + i0 + half * 16);
            float4 a0 = sa[0], a1 = sa[1];
            const float4* sbf = (const float4*)(W3 + (size_t)(k0 + r) * DD + i0 + half * 16);
            float4 f0 = sbf[0], f1 = sbf[1], f2v = sbf[2], f3 = sbf[3];
            float4* da = (float4*)&At[r][half * 16];
            da[0] = a0; da[1] = a1;
            short8 o0, o1;
            o0[0] = (short)f2b(f0.x); o0[1] = (short)f2b(f0.y); o0[2] = (short)f2b(f0.z); o0[3] = (short)f2b(f0.w);
            o0[4] = (short)f2b(f1.x); o0[5] = (short)f2b(f1.y); o0[6] = (short)f2b(f1.z); o0[7] = (short)f2b(f1.w);
            o1[0] = (short)f2b(f2v.x); o1[1] = (short)f2b(f2v.y); o1[2] = (short)f2b(f2v.z); o1[3] = (short)f2b(f2v.w);
            o1[4] = (short)f2b(f3.x); o1[5] = (short)f2b(f3.y); o1[6] = (short)f2b(f3.z); o1[7] = (short)f2b(f3.w);
            *(short8*)&Bt[r][half * 16] = o0;
            *(short8*)&Bt[r][half * 16 + 8] = o1;
        }
        __syncthreads();
        if (do_c1) {
            #pragma unroll
            for (int i = 0; i < 32; ++i) {
                float w1v = b2f(At[t][i]);
                c1acc += w1v * b3[i0 + i];
                a1acc += w1v * x0[i0 + i];
            }
        }
        short8 af[4], bf[4];
        #pragma unroll
        for (int a = 0; a < 4; ++a)
            af[a] = *(const short8*)&At[wr * 64 + a * 16 + fr][fg * 8];
        #pragma unroll
        for (int bq = 0; bq < 4; ++bq)
            bf[bq] = *(const short8*)&Bt[wc * 64 + bq * 16 + fr][fg * 8];
        #pragma unroll
        for (int a = 0; a < 4; ++a)
            #pragma unroll
            for (int bq = 0; bq < 4; ++bq)
                acc[a][bq] = __builtin_amdgcn_mfma_f32_16x16x32_bf16(af[a], bf[bq], acc[a][bq], 0, 0, 0);
        __syncthreads();
    }
    if (do_c1) { c1[m0 + t] = c1acc; A1g[m0 + t] = a1acc; }
    #pragma unroll
    for (int a = 0; a < 4; ++a) {
        #pragma unroll
        for (int bq = 0; bq < 4; ++bq) {
            #pragma unroll
            for (int j = 0; j < 4; ++j) {
                int row = m0 + wr * 64 + a * 16 + fg * 4 + j;
                int col = k0 + wc * 64 + bq * 16 + fr;
                size_t idx = (size_t)row * HH + col;
                float m = acc[a][bq][j];
                Mb[idx] = f2b(m);
                Pb[idx] = f2b(m * W2[idx]);
            }
        }
    }
}

// ---------------- fence-free grid barrier ----------------
// sync layout (uints): flags[b]=b*16 (0..4095) | sgen[sec]=4096+sec*16 |
// divacc[sec]=4352+sec*16 | divcnt=4608
// Producers' data stores are LLC-acked before s_barrier (compiler vmcnt drain),
// all cross-block data uses relaxed agent atomics (coherent at LLC) -> no fences.
// Block 0's wave 1 doubles as the checker (no extra block).
__device__ __forceinline__ void gbar(unsigned* sync, int b, unsigned g) {
    __syncthreads();
    const int t = threadIdx.x;
    if (b == 0 && t >= 64 && t < 128) {
        const int l = t - 64;
        while (true) {
            bool ok = true;
            #pragma unroll
            for (int k = 0; k < 4; ++k) {
                unsigned f = __hip_atomic_load(&sync[(l + (k << 6)) << 4],
                                               __ATOMIC_RELAXED, __HIP_MEMORY_SCOPE_AGENT);
                ok &= (f >= g);
            }
            if (!__any((int)(!ok))) break;
            __builtin_amdgcn_s_sleep(1);
        }
        if (l < 16)
            __hip_atomic_store(&sync[4096 + (l << 4)], g, __ATOMIC_RELAXED, __HIP_MEMORY_SCOPE_AGENT);
    }
    if (t == 0) {
        asm volatile("s_waitcnt vmcnt(0)" ::: "memory");
        __hip_atomic_store(&sync[b << 4], g, __ATOMIC_RELAXED, __HIP_MEMORY_SCOPE_AGENT);
        while (__hip_atomic_load(&sync[4096 + ((b & 15) << 4)],
                                 __ATOMIC_RELAXED, __HIP_MEMORY_SCOPE_AGENT) < g)
            __builtin_amdgcn_s_sleep(2);
    }
    __syncthreads();
}

// ---------------- persistent RK4 chain: all weights in LDS, atomic h-exchange ----------------
__global__ __launch_bounds__(256, 1) void k_chain(
    const unsigned short* __restrict__ Mb,   // [2048][2048]
    const unsigned short* __restrict__ Pb,   // [2048][2048]
    const unsigned short* __restrict__ W2T,  // [2048][2048]
    const unsigned short* __restrict__ W3T,  // [1024][2048]
    const float* __restrict__ x0,
    const float* __restrict__ b1, const float* __restrict__ wt,
    const float* __restrict__ b2, const float* __restrict__ b3,
    const float* __restrict__ c1, const float* __restrict__ A1g,
    float* __restrict__ h1_g, float* __restrict__ h2_g, float* __restrict__ hacc_g,
    float* __restrict__ out,
    unsigned* __restrict__ sync) {
    __shared__ unsigned short Ms[8][2048];   // 32 KB
    __shared__ unsigned short Ps[8][2048];   // 32 KB
    __shared__ unsigned short Qs[8][2048];   // 32 KB (W2T rows)
    __shared__ float vecH[2048];             // 8 KB
    __shared__ float vecW[2048];             // 8 KB
    __shared__ float wred[4];
    const int t = threadIdx.x, b = blockIdx.x;
    const int wib = t >> 6, lane = t & 63;
    const int gw2 = (b << 3) + (wib << 1);    // 2 h-rows per wave
    const int jx = (b << 2) + wib;            // 1 x-row per wave
    unsigned g = 0;

    // ---- preload this block's weight rows into LDS (wave-private) ----
    {
        const unsigned short* mp = Mb + (size_t)gw2 * HH;
        const unsigned short* pp = Pb + (size_t)gw2 * HH;
        const unsigned short* qp = W2T + (size_t)gw2 * HH;
        #pragma unroll
        for (int rep = 0; rep < 4; ++rep) {
            const int idx = rep * 512 + lane * 8;
            *(short8*)&Ms[wib * 2][idx]     = *(const short8*)(mp + idx);
            *(short8*)&Ms[wib * 2 + 1][idx] = *(const short8*)(mp + HH + idx);
            *(short8*)&Ps[wib * 2][idx]     = *(const short8*)(pp + idx);
            *(short8*)&Ps[wib * 2 + 1][idx] = *(const short8*)(pp + HH + idx);
            *(short8*)&Qs[wib * 2][idx]     = *(const short8*)(qp + idx);
            *(short8*)&Qs[wib * 2 + 1][idx] = *(const short8*)(qp + HH + idx);
        }
    }

    const float bb1_0 = b1[gw2], bb1_1 = b1[gw2 + 1];
    const float wt_0 = wt[gw2], wt_1 = wt[gw2 + 1];
    const float bb2_0 = b2[gw2], bb2_1 = b2[gw2 + 1];
    const float c1_0 = c1[gw2], c1_1 = c1[gw2 + 1];

    float A1_0 = 0.f, A1_1 = 0.f;
    float u0 = 0.f, u1 = 0.f;
    float hc0 = 0.f, hc1 = 0.f;
    float wdiv = 0.f;

    float logq_r = 0.f;
    if (b == 0 && wib == 0) {
        float ssum = 0.f;
        #pragma unroll
        for (int q = 0; q < 16; ++q) { float xv = x0[lane + (q << 6)]; ssum += xv * xv; }
        #pragma unroll
        for (int o = 1; o < 64; o <<= 1) ssum += __shfl_xor(ssum, o, 64);
        logq_r = -0.5f * ssum - 0.5f * 1024.0f * 1.8378770664093453f;
    }

    for (int s = 0; s < 8; ++s) {
        const int ss = s & 3;
        const float tcur = (s >> 2) * 0.5f + ((ss == 0) ? 0.f : (ss == 3) ? 0.5f : 0.25f);

        // ================= Phase A: h1 (+ div ride-along for stage s-1) =================
        if (s == 0) {
            A1_0 = A1g[gw2]; A1_1 = A1g[gw2 + 1];
            float h0 = tanhf(A1_0 + bb1_0 + tcur * wt_0);
            float h1v = tanhf(A1_1 + bb1_1 + tcur * wt_1);
            u0 = 1.f - h0 * h0; u1 = 1.f - h1v * h1v;
            if (lane == 0) { ast(h1_g + gw2, h0); ast(h1_g + gw2 + 1, h1v); }
        } else {
            #pragma unroll
            for (int q = 0; q < 8; ++q) {
                int i = t + (q << 8);
                float h2v = ald(h2_g + i);
                float sv = (ss == 0) ? ald(hacc_g + i) : h2v;
                vecH[i] = sv;
                vecW[i] = 1.f - h2v * h2v;
            }
            __syncthreads();
            float md0 = 0.f, md1 = 0.f, pd0 = 0.f, pd1 = 0.f;
            #pragma unroll
            for (int rep = 0; rep < 4; ++rep) {
                const int idx = rep * 512 + lane * 8;
                float4 hA = *(const float4*)(vecH + idx);
                float4 hB = *(const float4*)(vecH + idx + 4);
                float4 wA = *(const float4*)(vecW + idx);
                float4 wB = *(const float4*)(vecW + idx + 4);
                float hv[8] = {hA.x, hA.y, hA.z, hA.w, hB.x, hB.y, hB.z, hB.w};
                float wv[8] = {wA.x, wA.y, wA.z, wA.w, wB.x, wB.y, wB.z, wB.w};
                short8 m0v = *(const short8*)&Ms[wib * 2][idx];
                short8 m1v = *(const short8*)&Ms[wib * 2 + 1][idx];
                short8 p0v = *(const short8*)&Ps[wib * 2][idx];
                short8 p1v = *(const short8*)&Ps[wib * 2 + 1][idx];
                #pragma unroll
                for (int e = 0; e < 8; ++e) {
                    md0 += b2f((unsigned short)m0v[e]) * hv[e];
                    md1 += b2f((unsigned short)m1v[e]) * hv[e];
                    pd0 += b2f((unsigned short)p0v[e]) * wv[e];
                    pd1 += b2f((unsigned short)p1v[e]) * wv[e];
                }
            }
            #pragma unroll
            for (int o = 1; o < 64; o <<= 1) {
                md0 += __shfl_xor(md0, o, 64); md1 += __shfl_xor(md1, o, 64);
                pd0 += __shfl_xor(pd0, o, 64); pd1 += __shfl_xor(pd1, o, 64);
            }
            const int sp = (s - 1) & 3;
            const float cprev = (sp == 1 || sp == 2) ? (1.f / 6.f) : (1.f / 12.f);
            wdiv += cprev * (u0 * pd0 + u1 * pd1);
            float pre0, pre1;
            if (ss == 0) {                      // step boundary: A1 += M*hacc + dt*c1
                A1_0 += md0 + 0.5f * c1_0; A1_1 += md1 + 0.5f * c1_1;
                pre0 = A1_0 + bb1_0 + tcur * wt_0; pre1 = A1_1 + bb1_1 + tcur * wt_1;
            } else {
                const float a = (ss == 3) ? 0.5f : 0.25f;
                pre0 = A1_0 + a * (md0 + c1_0) + bb1_0 + tcur * wt_0;
                pre1 = A1_1 + a * (md1 + c1_1) + bb1_1 + tcur * wt_1;
            }
            float h0 = tanhf(pre0), h1v = tanhf(pre1);
            u0 = 1.f - h0 * h0; u1 = 1.f - h1v * h1v;
            if (lane == 0) { ast(h1_g + gw2, h0); ast(h1_g + gw2 + 1, h1v); }
        }
        gbar(sync, b, ++g);

        // ================= Phase B: h2 = tanh(W2^T h1 + b2) =================
        #pragma unroll
        for (int q = 0; q < 8; ++q) {
            int i = t + (q << 8);
            vecH[i] = ald(h1_g + i);
        }
        __syncthreads();
        {
            float a0 = 0.f, a1 = 0.f;
            #pragma unroll
            for (int rep = 0; rep < 4; ++rep) {
                const int idx = rep * 512 + lane * 8;
                float4 hA = *(const float4*)(vecH + idx);
                float4 hB = *(const float4*)(vecH + idx + 4);
                float hv[8] = {hA.x, hA.y, hA.z, hA.w, hB.x, hB.y, hB.z, hB.w};
                short8 r0 = *(const short8*)&Qs[wib * 2][idx];
                short8 r1 = *(const short8*)&Qs[wib * 2 + 1][idx];
                #pragma unroll
                for (int e = 0; e < 8; ++e) {
                    a0 += b2f((unsigned short)r0[e]) * hv[e];
                    a1 += b2f((unsigned short)r1[e]) * hv[e];
                }
            }
            #pragma unroll
            for (int o = 1; o < 64; o <<= 1) {
                a0 += __shfl_xor(a0, o, 64); a1 += __shfl_xor(a1, o, 64);
            }
            float q0 = tanhf(a0 + bb2_0), q1 = tanhf(a1 + bb2_1);
            const float cs = (ss == 1 || ss == 2) ? (1.f / 6.f) : (1.f / 12.f);
            hc0 += cs * q0; hc1 += cs * q1;
            if (lane == 0) {
                ast(h2_g + gw2, q0); ast(h2_g + gw2 + 1, q1);
                if (ss == 3) { ast(hacc_g + gw2, hc0); ast(hacc_g + gw2 + 1, hc1); }
            }
        }
        gbar(sync, b, ++g);
    }

    // ================= Epilogue: last div + x_out; logq via divcnt poll =================
    {
        #pragma unroll
        for (int q = 0; q < 8; ++q) {
            int i = t + (q << 8);
            float h2v = ald(h2_g + i);
            vecH[i] = ald(hacc_g + i);
            vecW[i] = 1.f - h2v * h2v;
        }
        __syncthreads();
        float pd0 = 0.f, pd1 = 0.f, xo = 0.f;
        const unsigned short* Vr = W3T + (size_t)jx * HH;
        #pragma unroll
        for (int rep = 0; rep < 4; ++rep) {
            const int idx = rep * 512 + lane * 8;
            float4 cA = *(const float4*)(vecH + idx);
            float4 cB = *(const float4*)(vecH + idx + 4);
            float4 wA = *(const float4*)(vecW + idx);
            float4 wB = *(const float4*)(vecW + idx + 4);
            float cv[8] = {cA.x, cA.y, cA.z, cA.w, cB.x, cB.y, cB.z, cB.w};
            float wv[8] = {wA.x, wA.y, wA.z, wA.w, wB.x, wB.y, wB.z, wB.w};
            short8 p0v = *(const short8*)&Ps[wib * 2][idx];
            short8 p1v = *(const short8*)&Ps[wib * 2 + 1][idx];
            short8 vv = *(const short8*)(Vr + idx);
            #pragma unroll
            for (int e = 0; e < 8; ++e) {
                pd0 += b2f((unsigned short)p0v[e]) * wv[e];
                pd1 += b2f((unsigned short)p1v[e]) * wv[e];
                xo  += b2f((unsigned short)vv[e]) * cv[e];
            }
        }
        #pragma unroll
        for (int o = 1; o < 64; o <<= 1) {
            pd0 += __shfl_xor(pd0, o, 64); pd1 += __shfl_xor(pd1, o, 64);
            xo += __shfl_xor(xo, o, 64);
        }
        wdiv += (1.f / 12.f) * (u0 * pd0 + u1 * pd1);
        if (lane == 0) {
            out[jx] = x0[jx] + xo + b3[jx];
            wred[wib] = wdiv;
        }
    }
    __syncthreads();
    if (t == 0) {
        float dsum = wred[0] + wred[1] + wred[2] + wred[3];
        atomicAdd((float*)(sync + 4352 + (b & 15) * 16), dsum);
        asm volatile("s_waitcnt vmcnt(0)" ::: "memory");
        atomicAdd(sync + 4608, 1u);
    }
    if (b == 0 && wib == 0) {
        if (lane < 16) {
            while (__hip_atomic_load(sync + 4608, __ATOMIC_RELAXED, __HIP_MEMORY_SCOPE_AGENT) < NCB)
                __builtin_amdgcn_s_sleep(2);
        }
        float v = 0.f;
        if (lane < 16) {
            unsigned du = __hip_atomic_load(sync + 4352 + lane * 16,
                                            __ATOMIC_RELAXED, __HIP_MEMORY_SCOPE_AGENT);
            v = __uint_as_float(du);
        }
        #pragma unroll
        for (int o = 1; o < 64; o <<= 1) v += __shfl_xor(v, o, 64);
        if (lane == 0) out[DD] = logq_r - v;
    }
}

extern "C" void kernel_launch(void* const* d_in, const int* in_sizes, int n_in,
                              void* d_out, int out_size, void* d_ws, size_t ws_size,
                              hipStream_t stream) {
    const float* x0 = (const float*)d_in[0];
    const float* W1 = (const float*)d_in[1];
    const float* b1 = (const float*)d_in[2];
    const float* wt = (const float*)d_in[3];
    const float* W2 = (const float*)d_in[4];
    const float* b2 = (const float*)d_in[5];
    const float* W3 = (const float*)d_in[6];
    const float* b3 = (const float*)d_in[7];
    float* out = (float*)d_out;

    char* ws = (char*)d_ws;
    const size_t MB = 1024 * 1024;
    unsigned short* Pb  = (unsigned short*)(ws);            // 8 MB
    unsigned short* W1T = (unsigned short*)(ws + 8 * MB);   // 4 MB
    unsigned short* W2T = (unsigned short*)(ws + 12 * MB);  // 8 MB
    unsigned short* W3T = (unsigned short*)(ws + 20 * MB);  // 4 MB
    unsigned short* Mb  = (unsigned short*)(ws + 24 * MB);  // 8 MB
    float* fb = (float*)(ws + 32 * MB);
    float* h1_g    = fb;                       // 2048
    float* h2_g    = fb + 2048;                // 2048
    float* hacc_g  = fb + 4096;                // 2048
    float* c1      = fb + 6144;                // 2048
    float* A1g     = fb + 8192;                // 2048
    unsigned* sync = (unsigned*)(fb + 10240);  // 4624 uints

    k_preW1<<<512, 256, 0, stream>>>(W1, W1T, sync);
    k_gemmPT<<<1792, 256, 0, stream>>>(W1T, W2, W3, b3, x0, Mb, Pb, W2T, W3T, c1, A1g);
    k_chain<<<NCB, 256, 0, stream>>>(Mb, Pb, W2T, W3T, x0, b1, wt, b2, b3, c1, A1g,
                                     h1_g, h2_g, hacc_g, out, sync);
}